// Round 3
// baseline (200.430 us; speedup 1.0000x reference)
//
#include <hip/hip_runtime.h>
#include <math.h>

// ---------------------------------------------------------------------------
// Fused 11-layer funnel MLP, round 6.
// Round-5 post-mortem: LDS pipe ~88% busy; weight A-frag re-reads (70 of 90
// b128/wave-chunk) dominate and are paid PER 16 ROWS. Register file full
// (64 arch VGPR + 64 AGPR persistent frags = 128 @ 4 waves/SIMD).
// Round 6: 32 rows/wave (weight reads amortized 2x) at 10 waves:
//  - Reg-only layers (L2, L7-L10, 16 KB) no longer keep persistent LDS
//    copies: staged through the startup-dead arena region, preloaded to
//    registers, then the space is reused as arenas. Persistent weights
//    88 -> 71.7 KB, so 10 waves x 8 KB arenas fit in 153.6 KB.
//  - acc[NMT][2] / two B-halves per chunk (round-3 ILP) + round-5 minimal
//    pad writes. LDS demand/CU: ~164k -> ~107k cycles.
//  - launch_bounds(640,3): <=168 regs/wave so a 10-wave block fits 3/SIMD.
//  - 320 rows/block doesn't divide 2^19: clamped x loads + guarded stores.
// ---------------------------------------------------------------------------

using bf16x8 = __attribute__((ext_vector_type(8))) short;   // 8 bf16 = 4 VGPRs
using f32x4  = __attribute__((ext_vector_type(4))) float;
using u16x8  = __attribute__((ext_vector_type(8))) unsigned short;
using u32x2  = __attribute__((ext_vector_type(2))) unsigned;
typedef __bf16 bf16x2_t __attribute__((ext_vector_type(2)));

namespace {
constexpr int NL = 11;
constexpr int IN_[NL]   = {15, 30, 60, 90, 120, 90, 60, 30, 15, 10, 5};
constexpr int OUT_[NL]  = {30, 60, 90, 120, 90, 60, 30, 15, 10, 5, 1};
constexpr int KP_[NL]   = {32, 32, 64, 96, 128, 96, 64, 32, 32, 32, 32};  // in, pad 32
constexpr int NP_[NL]   = {32, 64, 96, 128, 96, 64, 32, 16, 16, 16, 16};  // out, pad 16
// Persistent LDS weight offsets (shorts): L0,L1,L3,L4,L5,L6 only.
constexpr int WP0 = 0;        // 1024
constexpr int WP1 = 1024;     // 2048
constexpr int WP3 = 3072;     // 12288
constexpr int WP4 = 15360;    // 12288
constexpr int WP5 = 27648;    // 6144
constexpr int WP6 = 33792;    // 2048
constexpr int WTOT = 35840;   // shorts (71.7 KB)
// Temp staging offsets within the arena region (reg-only layers).
constexpr int T2  = 0;        // 6144
constexpr int T7  = 6144;     // 512
constexpr int T8  = 6656;
constexpr int T9  = 7168;
constexpr int T10 = 7680;     // end 8192 <= arena space
constexpr int WAVES   = 10;
constexpr int THREADS = WAVES * 64;                   // 640
constexpr int ROWS_PER_WAVE  = 32;
constexpr int ROWS_PER_BLOCK = WAVES * ROWS_PER_WAVE; // 320
constexpr int ARENA   = 4096;   // shorts per wave (8 KB)
constexpr int LDS_BYTES = (WTOT + WAVES * ARENA) * 2; // 153600
}

// fp32 -> bf16 RNE (scalar, staging only)
__device__ __forceinline__ unsigned short f2bf(float f) {
    unsigned u = __float_as_uint(f);
    u += 0x7fffu + ((u >> 16) & 1u);
    return (unsigned short)(u >> 16);
}

// packed fp32x2 -> bf16x2 (RNE); gfx950 has v_cvt_pk_bf16_f32
__device__ __forceinline__ unsigned pk2(float a, float b) {
#if __has_builtin(__builtin_amdgcn_cvt_pk_bf16_f32)
    return __builtin_bit_cast(unsigned, __builtin_amdgcn_cvt_pk_bf16_f32(a, b));
#else
    bf16x2_t c;
    c[0] = (__bf16)a;
    c[1] = (__bf16)b;
    return __builtin_bit_cast(unsigned, c);
#endif
}

// Stage layer L's weights (A-frag-major) with bias/one-hot pads folded in.
// dst points at the layer's own region (persistent or temp).
template <int L>
__device__ __forceinline__ void stage_w(const float* __restrict__ W,
                                        const float* __restrict__ B,
                                        short* dst, int tid) {
    constexpr int KP = KP_[L], NP = NP_[L], INl = IN_[L], OUTl = OUT_[L];
    constexpr int NKT = KP / 32;
    for (int idx = tid; idx < NP * KP; idx += THREADS) {
        const int f    = idx >> 9;
        const int t    = idx & 511;
        const int quad = t >> 7;
        const int colc = (t >> 3) & 15;
        const int j    = t & 7;
        const int mt   = f / NKT;
        const int kt   = f - mt * NKT;
        const int m    = mt * 16 + colc;
        const int k    = kt * 32 + quad * 8 + j;
        float v = 0.f;
        if (m < OUTl) {
            if (k < INl) v = W[m * INl + k];
            else if (k == INl) v = B[m];                    // f2bf -> bias_hi
            else if (k == INl + 1) {                        // bias_lo
                float hf = __builtin_bit_cast(float, (unsigned)f2bf(B[m]) << 16);
                v = B[m] - hf;
            }
        } else if (m == OUTl || m == OUTl + 1) {
            if (k == INl) v = 1.f;                          // 1.0-generator row
        }
        dst[idx] = (short)f2bf(v);
    }
}

// One Linear+ReLU layer over this wave's 32 rows (two 16-row halves),
// in place in `buf`. k-outer, all 2*NMT accumulator chains live.
template <int L>
__device__ __forceinline__ void layer_fwd(const short* __restrict__ wl,
                                          short* buf, int col, int quad) {
    constexpr int KP   = KP_[L];
    constexpr int NP   = NP_[L];
    constexpr int NKT  = KP / 32;
    constexpr int NMT  = NP / 16;
    constexpr int NKTN = KP_[L + 1] / 32;
    const int fo = quad * 128 + col * 8;

    f32x4 acc[NMT][2];
#pragma unroll
    for (int mt = 0; mt < NMT; ++mt)
#pragma unroll
        for (int b = 0; b < 2; ++b)
            acc[mt][b] = f32x4{0.f, 0.f, 0.f, 0.f};

#pragma unroll
    for (int kt = 0; kt < NKT; ++kt) {
        bf16x8 b0 = *(const bf16x8*)(buf + kt * 512 + fo);
        bf16x8 b1 = *(const bf16x8*)(buf + (NKT + kt) * 512 + fo);
#pragma unroll
        for (int mt = 0; mt < NMT; ++mt) {
            bf16x8 af = *(const bf16x8*)(wl + (mt * NKT + kt) * 512 + fo);
            acc[mt][0] = __builtin_amdgcn_mfma_f32_16x16x32_bf16(af, b0, acc[mt][0], 0, 0, 0);
            acc[mt][1] = __builtin_amdgcn_mfma_f32_16x16x32_bf16(af, b1, acc[mt][1], 0, 0, 0);
        }
    }
#pragma unroll
    for (int mt = 0; mt < NMT; ++mt) {
        const int wbase = (mt >> 1) * 512 + ((mt & 1) * 2 + (quad >> 1)) * 128 + col * 8 + (quad & 1) * 4;
#pragma unroll
        for (int b = 0; b < 2; ++b) {
            u32x2 o;
            o[0] = pk2(fmaxf(acc[mt][b][0], 0.f), fmaxf(acc[mt][b][1], 0.f));
            o[1] = pk2(fmaxf(acc[mt][b][2], 0.f), fmaxf(acc[mt][b][3], 0.f));
            *(u32x2*)(buf + b * NKTN * 512 + wbase) = o;
        }
    }
    // NP_[L] == KP_[L+1] for L0..L6: no pad writes needed.
}

// Same body with the 12 L2 weight frags preloaded in registers.
__device__ __forceinline__ void layer2_pre(const bf16x8 (&wf)[12],
                                           short* buf, int col, int quad) {
    constexpr int NKT = 2, NMT = 6, NKTN = 3;   // KP=64, NP=96, next KP=96
    const int fo = quad * 128 + col * 8;
    f32x4 acc[NMT][2];
#pragma unroll
    for (int mt = 0; mt < NMT; ++mt)
#pragma unroll
        for (int b = 0; b < 2; ++b)
            acc[mt][b] = f32x4{0.f, 0.f, 0.f, 0.f};
#pragma unroll
    for (int kt = 0; kt < NKT; ++kt) {
        bf16x8 b0 = *(const bf16x8*)(buf + kt * 512 + fo);
        bf16x8 b1 = *(const bf16x8*)(buf + (NKT + kt) * 512 + fo);
#pragma unroll
        for (int mt = 0; mt < NMT; ++mt) {
            acc[mt][0] = __builtin_amdgcn_mfma_f32_16x16x32_bf16(wf[mt * NKT + kt], b0, acc[mt][0], 0, 0, 0);
            acc[mt][1] = __builtin_amdgcn_mfma_f32_16x16x32_bf16(wf[mt * NKT + kt], b1, acc[mt][1], 0, 0, 0);
        }
    }
#pragma unroll
    for (int mt = 0; mt < NMT; ++mt) {
        const int wbase = (mt >> 1) * 512 + ((mt & 1) * 2 + (quad >> 1)) * 128 + col * 8 + (quad & 1) * 4;
#pragma unroll
        for (int b = 0; b < 2; ++b) {
            u32x2 o;
            o[0] = pk2(fmaxf(acc[mt][b][0], 0.f), fmaxf(acc[mt][b][1], 0.f));
            o[1] = pk2(fmaxf(acc[mt][b][2], 0.f), fmaxf(acc[mt][b][3], 0.f));
            *(u32x2*)(buf + b * NKTN * 512 + wbase) = o;
        }
    }
}

// Single-tile 32->16 layer (L7/L8/L9), both halves, preloaded weight frag.
// Pad: only k==16 (bias_lo col) needs 1.0 -- padded weight cols in [17,32)
// are zero, so leftover finite bf16 there contributes 0.
__device__ __forceinline__ void layer_one(bf16x8 af, short* buf, int col, int quad) {
    const int fo = quad * 128 + col * 8;
    bf16x8 b0 = *(const bf16x8*)(buf + fo);
    bf16x8 b1 = *(const bf16x8*)(buf + 512 + fo);
    f32x4 a0 = f32x4{0.f, 0.f, 0.f, 0.f};
    f32x4 a1 = f32x4{0.f, 0.f, 0.f, 0.f};
    a0 = __builtin_amdgcn_mfma_f32_16x16x32_bf16(af, b0, a0, 0, 0, 0);
    a1 = __builtin_amdgcn_mfma_f32_16x16x32_bf16(af, b1, a1, 0, 0, 0);
    const int wbase = (quad >> 1) * 128 + col * 8 + (quad & 1) * 4;
    u32x2 o0, o1;
    o0[0] = pk2(fmaxf(a0[0], 0.f), fmaxf(a0[1], 0.f));
    o0[1] = pk2(fmaxf(a0[2], 0.f), fmaxf(a0[3], 0.f));
    o1[0] = pk2(fmaxf(a1[0], 0.f), fmaxf(a1[1], 0.f));
    o1[1] = pk2(fmaxf(a1[2], 0.f), fmaxf(a1[3], 0.f));
    *(u32x2*)(buf + wbase) = o0;
    *(u32x2*)(buf + 512 + wbase) = o1;
    if (quad == 0) {
        buf[256 + col * 8]       = (short)0x3F80;   // half 0: k==16 := 1.0
        buf[512 + 256 + col * 8] = (short)0x3F80;   // half 1
    }
}

__device__ __forceinline__ float4 ld4(const float* p) {
    float4 t;
    __builtin_memcpy(&t, p, 16);
    return t;
}

// Fetch this wave's two x row-fragments, rows clamped to nrows-1.
__device__ __forceinline__ void fetch_x(const float* __restrict__ x, int row0,
                                        int nrows, int col, int quad,
                                        float4& a0, float4& a1) {
    int r0 = row0 + col;      if (r0 > nrows - 1) r0 = nrows - 1;
    int r1 = row0 + 16 + col; if (r1 > nrows - 1) r1 = nrows - 1;
    const float* p0 = x + (long)r0 * 15;
    const float* p1 = x + (long)r1 * 15;
    if (quad < 3) {
        a0 = ld4(p0 + quad * 4);
        a1 = ld4(p1 + quad * 4);
    } else {
        // k = 12..14 + bias-col 1.0 at k=15 (load at +11 to stay in bounds)
        float4 t0 = ld4(p0 + 11), t1 = ld4(p1 + 11);
        a0 = make_float4(t0.y, t0.z, t0.w, 1.f);
        a1 = make_float4(t1.y, t1.z, t1.w, 1.f);
    }
}

__device__ __forceinline__ void stage_x(short* buf, float4 a0, float4 a1,
                                        int col, int quad) {
    const int off = (quad >> 1) * 128 + col * 8 + (quad & 1) * 4;
    u32x2 o0, o1;
    o0[0] = pk2(a0.x, a0.y); o0[1] = pk2(a0.z, a0.w);
    o1[0] = pk2(a1.x, a1.y); o1[1] = pk2(a1.z, a1.w);
    *(u32x2*)(buf + off) = o0;
    *(u32x2*)(buf + 512 + off) = o1;
    // bias_lo column of layer 0: k==16 := 1.0; [17,32) are don't-care.
    if (quad == 0) {
        buf[256 + col * 8]       = (short)0x3F80;
        buf[512 + 256 + col * 8] = (short)0x3F80;
    }
}

extern "C" __global__ void __launch_bounds__(THREADS, 3)
mlp_fused(const float* __restrict__ x,
          const float* __restrict__ W0,  const float* __restrict__ B0,
          const float* __restrict__ W1,  const float* __restrict__ B1,
          const float* __restrict__ W2,  const float* __restrict__ B2,
          const float* __restrict__ W3,  const float* __restrict__ B3,
          const float* __restrict__ W4,  const float* __restrict__ B4,
          const float* __restrict__ W5,  const float* __restrict__ B5,
          const float* __restrict__ W6,  const float* __restrict__ B6,
          const float* __restrict__ W7,  const float* __restrict__ B7,
          const float* __restrict__ W8,  const float* __restrict__ B8,
          const float* __restrict__ W9,  const float* __restrict__ B9,
          const float* __restrict__ W10, const float* __restrict__ B10,
          float* __restrict__ out, int nchunks, int nrows) {
    extern __shared__ short smem[];
    short* wlds = smem;
    short* act  = smem + WTOT;

    const int tid = threadIdx.x;

    // Persistent LDS weights.
    stage_w<0>(W0, B0, wlds + WP0, tid);
    stage_w<1>(W1, B1, wlds + WP1, tid);
    stage_w<3>(W3, B3, wlds + WP3, tid);
    stage_w<4>(W4, B4, wlds + WP4, tid);
    stage_w<5>(W5, B5, wlds + WP5, tid);
    stage_w<6>(W6, B6, wlds + WP6, tid);
    // Reg-only layers staged through the (startup-dead) arena region.
    stage_w<2>(W2, B2, act + T2, tid);
    stage_w<7>(W7, B7, act + T7, tid);
    stage_w<8>(W8, B8, act + T8, tid);
    stage_w<9>(W9, B9, act + T9, tid);
    stage_w<10>(W10, B10, act + T10, tid);
    __syncthreads();

    const int wave = tid >> 6;
    const int lane = tid & 63;
    const int col  = lane & 15;
    const int quad = lane >> 4;
    short* buf = act + wave * ARENA;
    const int fo = quad * 128 + col * 8;

    // Preload reg-only weight frags, then reclaim the staging space.
    bf16x8 wf2[12];
#pragma unroll
    for (int i = 0; i < 12; ++i)
        wf2[i] = *(const bf16x8*)(act + T2 + i * 512 + fo);
    const bf16x8 w7  = *(const bf16x8*)(act + T7  + fo);
    const bf16x8 w8  = *(const bf16x8*)(act + T8  + fo);
    const bf16x8 w9  = *(const bf16x8*)(act + T9  + fo);
    const bf16x8 w10 = *(const bf16x8*)(act + T10 + fo);
    __syncthreads();   // all reads done before arenas are reused

    // One-time arena zero: guards don't-care B regions against NaN
    // patterns (NaN * 0-weight = NaN in MFMA). Own arena only.
    {
        u16x8 z = {0, 0, 0, 0, 0, 0, 0, 0};
#pragma unroll
        for (int i = 0; i < 8; ++i)
            *(u16x8*)(buf + (lane + i * 64) * 8) = z;
    }

    int chunk = blockIdx.x;
    float4 xa, xb;
    if (chunk < nchunks)
        fetch_x(x, chunk * ROWS_PER_BLOCK + wave * ROWS_PER_WAVE, nrows, col, quad, xa, xb);

    for (; chunk < nchunks; chunk += gridDim.x) {
        const int row0 = chunk * ROWS_PER_BLOCK + wave * ROWS_PER_WAVE;
        stage_x(buf, xa, xb, col, quad);

        // Prefetch next chunk's x while the layer stack runs.
        const int nxt = chunk + gridDim.x;
        if (nxt < nchunks)
            fetch_x(x, nxt * ROWS_PER_BLOCK + wave * ROWS_PER_WAVE, nrows, col, quad, xa, xb);

        layer_fwd<0>(wlds + WP0, buf, col, quad);
        layer_fwd<1>(wlds + WP1, buf, col, quad);
        layer2_pre(wf2, buf, col, quad);
        layer_fwd<3>(wlds + WP3, buf, col, quad);
        layer_fwd<4>(wlds + WP4, buf, col, quad);
        layer_fwd<5>(wlds + WP5, buf, col, quad);
        layer_fwd<6>(wlds + WP6, buf, col, quad);
        layer_one(w7, buf, col, quad);
        layer_one(w8, buf, col, quad);
        layer_one(w9, buf, col, quad);

        // Final layer (5 -> 1, bias via pads) + sigmoid, guarded stores.
        {
            bf16x8 b0 = *(const bf16x8*)(buf + fo);
            bf16x8 b1 = *(const bf16x8*)(buf + 512 + fo);
            f32x4 a0 = f32x4{0.f, 0.f, 0.f, 0.f};
            f32x4 a1 = f32x4{0.f, 0.f, 0.f, 0.f};
            a0 = __builtin_amdgcn_mfma_f32_16x16x32_bf16(w10, b0, a0, 0, 0, 0);
            a1 = __builtin_amdgcn_mfma_f32_16x16x32_bf16(w10, b1, a1, 0, 0, 0);
            if (quad == 0) {
                const int r0 = row0 + col;
                const int r1 = row0 + 16 + col;
                if (r0 < nrows) out[r0] = 1.f / (1.f + __expf(-a0[0]));
                if (r1 < nrows) out[r1] = 1.f / (1.f + __expf(-a1[0]));
            }
        }
    }
}

extern "C" void kernel_launch(void* const* d_in, const int* in_sizes, int n_in,
                              void* d_out, int out_size, void* d_ws, size_t ws_size,
                              hipStream_t stream) {
    (void)n_in; (void)d_ws; (void)ws_size; (void)out_size;
    const float* x = (const float*)d_in[0];
    const float* W[11];
    const float* B[11];
    for (int i = 0; i < 11; ++i) {
        W[i] = (const float*)d_in[1 + 2 * i];
        B[i] = (const float*)d_in[2 + 2 * i];
    }
    const int nrows   = in_sizes[0] / 15;
    const int nchunks = (nrows + ROWS_PER_BLOCK - 1) / ROWS_PER_BLOCK; // 1639

    hipFuncSetAttribute((const void*)mlp_fused,
                        hipFuncAttributeMaxDynamicSharedMemorySize, LDS_BYTES);

    mlp_fused<<<dim3(256), dim3(THREADS), LDS_BYTES, stream>>>(
        x,
        W[0], B[0], W[1], B[1], W[2], B[2], W[3], B[3], W[4], B[4],
        W[5], B[5], W[6], B[6], W[7], B[7], W[8], B[8], W[9], B[9],
        W[10], B[10],
        (float*)d_out, nchunks, nrows);
}

// Round 4
// 189.147 us; speedup vs baseline: 1.0597x; 1.0597x over previous
//
#include <hip/hip_runtime.h>
#include <math.h>

// ---------------------------------------------------------------------------
// Fused 11-layer funnel MLP, round 7.
// Round-6 post-mortem: 32 rows/WAVE spilled (64 acc + 64 persistent regs vs
// 170 cap -> +25MB scratch HBM traffic) and 10 waves = uneven 2.5/SIMD.
// Round 7: pair-split. 16 waves as 8 pairs; each pair owns 32 rows (8KB
// arena). Within a pair, wave sub computes output channels
// [sub*N/2,(sub+1)*N/2) for all 32 rows:
//   - weight A-frag LDS bytes per row HALVED vs round 5 (read once / 32 rows)
//   - acc <= 32 VGPR (no spill), 16 waves = 4/SIMD even
//   - B-frags read by both waves (small term); pair shares arena =>
//     2 __syncthreads per big layer (read-done / write-done), 15/chunk.
//   - tails L7-L10 row-split (wave sub owns rows [sub*16,sub*16+16)) ->
//     barrier-free; weights in VGPRs.
// Retained: fragment-major conflict-free LDS, bias folded into MFMA pad
// columns, 1.0-generator rows, minimal k==16 pad writes + startup arena
// zero, v_cvt_pk_bf16_f32 epilogue, L2 half-frags + tails persistent in
// regs, x prefetch.
// ---------------------------------------------------------------------------

using bf16x8 = __attribute__((ext_vector_type(8))) short;   // 8 bf16 = 4 VGPRs
using f32x4  = __attribute__((ext_vector_type(4))) float;
using u16x8  = __attribute__((ext_vector_type(8))) unsigned short;
using u32x2  = __attribute__((ext_vector_type(2))) unsigned;
typedef __bf16 bf16x2_t __attribute__((ext_vector_type(2)));

namespace {
constexpr int NL = 11;
constexpr int IN_[NL]   = {15, 30, 60, 90, 120, 90, 60, 30, 15, 10, 5};
constexpr int OUT_[NL]  = {30, 60, 90, 120, 90, 60, 30, 15, 10, 5, 1};
constexpr int KP_[NL]   = {32, 32, 64, 96, 128, 96, 64, 32, 32, 32, 32};  // in, pad 32
constexpr int NP_[NL]   = {32, 64, 96, 128, 96, 64, 32, 16, 16, 16, 16};  // out, pad 16
constexpr int WOFF_[NL] = {0, 1024, 3072, 9216, 21504, 33792, 39936, 41984, 42496, 43008, 43520};
constexpr int WTOT      = 44032;   // shorts (88 KB)
constexpr int ACT_OFF   = WTOT;
constexpr int WAVES     = 16;
constexpr int THREADS   = WAVES * 64;                 // 1024
constexpr int PAIRS     = WAVES / 2;                  // 8
constexpr int ROWS_PER_PAIR  = 32;
constexpr int ROWS_PER_BLOCK = PAIRS * ROWS_PER_PAIR; // 256
constexpr int ARENA     = 4096;    // shorts per pair (8 KB, 32 rows x KP<=128)
constexpr int LDS_BYTES = (WTOT + PAIRS * ARENA) * 2; // 153600
}

// fp32 -> bf16 RNE (scalar, staging only)
__device__ __forceinline__ unsigned short f2bf(float f) {
    unsigned u = __float_as_uint(f);
    u += 0x7fffu + ((u >> 16) & 1u);
    return (unsigned short)(u >> 16);
}

// packed fp32x2 -> bf16x2 (RNE); gfx950 has v_cvt_pk_bf16_f32
__device__ __forceinline__ unsigned pk2(float a, float b) {
#if __has_builtin(__builtin_amdgcn_cvt_pk_bf16_f32)
    return __builtin_bit_cast(unsigned, __builtin_amdgcn_cvt_pk_bf16_f32(a, b));
#else
    bf16x2_t c;
    c[0] = (__bf16)a;
    c[1] = (__bf16)b;
    return __builtin_bit_cast(unsigned, c);
#endif
}

// Stage layer L's weights (A-frag-major) with bias/one-hot pads folded in.
template <int L>
__device__ __forceinline__ void stage_w(const float* __restrict__ W,
                                        const float* __restrict__ B,
                                        short* wlds, int tid) {
    constexpr int KP = KP_[L], NP = NP_[L], INl = IN_[L], OUTl = OUT_[L];
    constexpr int NKT = KP / 32;
    for (int idx = tid; idx < NP * KP; idx += THREADS) {
        const int f    = idx >> 9;
        const int t    = idx & 511;
        const int quad = t >> 7;
        const int colc = (t >> 3) & 15;
        const int j    = t & 7;
        const int mt   = f / NKT;
        const int kt   = f - mt * NKT;
        const int m    = mt * 16 + colc;
        const int k    = kt * 32 + quad * 8 + j;
        float v = 0.f;
        if (m < OUTl) {
            if (k < INl) v = W[m * INl + k];
            else if (k == INl) v = B[m];                    // f2bf -> bias_hi
            else if (k == INl + 1) {                        // bias_lo
                float hf = __builtin_bit_cast(float, (unsigned)f2bf(B[m]) << 16);
                v = B[m] - hf;
            }
        } else if (m == OUTl || m == OUTl + 1) {
            if (k == INl) v = 1.f;                          // 1.0-generator row
        }
        wlds[WOFF_[L] + idx] = (short)f2bf(v);
    }
}

// One Linear+ReLU layer over the pair's 32 rows; this wave computes output
// channel tiles mt in [sub*NMT/2, (sub+1)*NMT/2) for BOTH 16-row halves.
// Two block barriers: read-done (before in-place writes), write-done.
template <int L>
__device__ __forceinline__ void layer_pair(const short* __restrict__ wl,
                                           short* buf, int col, int quad, int sub) {
    constexpr int KP   = KP_[L];
    constexpr int NP   = NP_[L];
    constexpr int NKT  = KP / 32;
    constexpr int NMT  = NP / 16;
    constexpr int NMH  = NMT / 2;
    constexpr int NKTN = KP_[L + 1] / 32;
    const int fo = quad * 128 + col * 8;

    f32x4 acc[NMH][2];
#pragma unroll
    for (int m = 0; m < NMH; ++m)
#pragma unroll
        for (int b = 0; b < 2; ++b)
            acc[m][b] = f32x4{0.f, 0.f, 0.f, 0.f};

#pragma unroll
    for (int kt = 0; kt < NKT; ++kt) {
        bf16x8 b0 = *(const bf16x8*)(buf + kt * 512 + fo);
        bf16x8 b1 = *(const bf16x8*)(buf + (NKT + kt) * 512 + fo);
#pragma unroll
        for (int m = 0; m < NMH; ++m) {
            const int mt = sub * NMH + m;
            bf16x8 af = *(const bf16x8*)(wl + (mt * NKT + kt) * 512 + fo);
            acc[m][0] = __builtin_amdgcn_mfma_f32_16x16x32_bf16(af, b0, acc[m][0], 0, 0, 0);
            acc[m][1] = __builtin_amdgcn_mfma_f32_16x16x32_bf16(af, b1, acc[m][1], 0, 0, 0);
        }
    }
    __syncthreads();   // all waves' reads of this layer's inputs retired
#pragma unroll
    for (int m = 0; m < NMH; ++m) {
        const int mt = sub * NMH + m;
        const int wbase = (mt >> 1) * 512 + ((mt & 1) * 2 + (quad >> 1)) * 128 + col * 8 + (quad & 1) * 4;
#pragma unroll
        for (int b = 0; b < 2; ++b) {
            u32x2 o;
            o[0] = pk2(fmaxf(acc[m][b][0], 0.f), fmaxf(acc[m][b][1], 0.f));
            o[1] = pk2(fmaxf(acc[m][b][2], 0.f), fmaxf(acc[m][b][3], 0.f));
            *(u32x2*)(buf + b * NKTN * 512 + wbase) = o;
        }
    }
    __syncthreads();   // outputs visible to the partner wave
}

// Same body with the wave's 6 L2 half-frags preloaded in registers.
__device__ __forceinline__ void layer2_pair(const bf16x8 (&wf)[6],
                                            short* buf, int col, int quad, int sub) {
    constexpr int NKT = 2, NMH = 3, NKTN = 3;   // KP=64, NP=96 (half=48), next KP=96
    const int fo = quad * 128 + col * 8;
    f32x4 acc[NMH][2];
#pragma unroll
    for (int m = 0; m < NMH; ++m)
#pragma unroll
        for (int b = 0; b < 2; ++b)
            acc[m][b] = f32x4{0.f, 0.f, 0.f, 0.f};
#pragma unroll
    for (int kt = 0; kt < NKT; ++kt) {
        bf16x8 b0 = *(const bf16x8*)(buf + kt * 512 + fo);
        bf16x8 b1 = *(const bf16x8*)(buf + (NKT + kt) * 512 + fo);
#pragma unroll
        for (int m = 0; m < NMH; ++m) {
            acc[m][0] = __builtin_amdgcn_mfma_f32_16x16x32_bf16(wf[m * NKT + kt], b0, acc[m][0], 0, 0, 0);
            acc[m][1] = __builtin_amdgcn_mfma_f32_16x16x32_bf16(wf[m * NKT + kt], b1, acc[m][1], 0, 0, 0);
        }
    }
    __syncthreads();
#pragma unroll
    for (int m = 0; m < NMH; ++m) {
        const int mt = sub * NMH + m;
        const int wbase = (mt >> 1) * 512 + ((mt & 1) * 2 + (quad >> 1)) * 128 + col * 8 + (quad & 1) * 4;
#pragma unroll
        for (int b = 0; b < 2; ++b) {
            u32x2 o;
            o[0] = pk2(fmaxf(acc[m][b][0], 0.f), fmaxf(acc[m][b][1], 0.f));
            o[1] = pk2(fmaxf(acc[m][b][2], 0.f), fmaxf(acc[m][b][3], 0.f));
            *(u32x2*)(buf + b * NKTN * 512 + wbase) = o;
        }
    }
    __syncthreads();
}

// Single-tile 32->16 tail layer (L7/L8/L9): row-split, wave sub owns its
// 16-row half. Pad: only k==16 (bias_lo col) needs 1.0; k in [17,32) are
// don't-care (weight cols zero) and stay finite (startup zero / old data).
__device__ __forceinline__ void layer_one_half(bf16x8 af, short* buf,
                                               int col, int quad, int sub) {
    short* h = buf + sub * 512;
    const int fo = quad * 128 + col * 8;
    bf16x8 b0 = *(const bf16x8*)(h + fo);
    f32x4 a0 = f32x4{0.f, 0.f, 0.f, 0.f};
    a0 = __builtin_amdgcn_mfma_f32_16x16x32_bf16(af, b0, a0, 0, 0, 0);
    const int wbase = (quad >> 1) * 128 + col * 8 + (quad & 1) * 4;
    u32x2 o0;
    o0[0] = pk2(fmaxf(a0[0], 0.f), fmaxf(a0[1], 0.f));
    o0[1] = pk2(fmaxf(a0[2], 0.f), fmaxf(a0[3], 0.f));
    *(u32x2*)(h + wbase) = o0;
    if (quad == 0) h[256 + col * 8] = (short)0x3F80;   // k==16 := 1.0
}

__device__ __forceinline__ float4 ld4(const float* p) {
    float4 t;
    __builtin_memcpy(&t, p, 16);
    return t;
}

// Fetch this wave's 16-row-half x fragment for a chunk.
__device__ __forceinline__ void fetch_x(const float* __restrict__ x, int row0,
                                        int col, int quad, float4& a0) {
    const float* r0 = x + (long)(row0 + col) * 15;
    if (quad < 3) {
        a0 = ld4(r0 + quad * 4);
    } else {
        // k = 12..14 + bias-col 1.0 at k=15 (load at +11 to stay in bounds)
        float4 t0 = ld4(r0 + 11);
        a0 = make_float4(t0.y, t0.z, t0.w, 1.f);
    }
}

__device__ __forceinline__ void stage_x(short* buf, float4 a0,
                                        int col, int quad, int sub) {
    short* h = buf + sub * 512;
    const int off = (quad >> 1) * 128 + col * 8 + (quad & 1) * 4;
    u32x2 o0;
    o0[0] = pk2(a0.x, a0.y); o0[1] = pk2(a0.z, a0.w);
    *(u32x2*)(h + off) = o0;
    // bias_lo column of layer 0: k==16 := 1.0; [17,32) are don't-care.
    if (quad == 0) h[256 + col * 8] = (short)0x3F80;
}

extern "C" __global__ void __launch_bounds__(THREADS, 4)
mlp_fused(const float* __restrict__ x,
          const float* __restrict__ W0,  const float* __restrict__ B0,
          const float* __restrict__ W1,  const float* __restrict__ B1,
          const float* __restrict__ W2,  const float* __restrict__ B2,
          const float* __restrict__ W3,  const float* __restrict__ B3,
          const float* __restrict__ W4,  const float* __restrict__ B4,
          const float* __restrict__ W5,  const float* __restrict__ B5,
          const float* __restrict__ W6,  const float* __restrict__ B6,
          const float* __restrict__ W7,  const float* __restrict__ B7,
          const float* __restrict__ W8,  const float* __restrict__ B8,
          const float* __restrict__ W9,  const float* __restrict__ B9,
          const float* __restrict__ W10, const float* __restrict__ B10,
          float* __restrict__ out, int nchunks) {
    extern __shared__ short smem[];
    short* wlds = smem;
    short* act  = smem + ACT_OFF;

    const int tid = threadIdx.x;

    stage_w<0>(W0, B0, wlds, tid);
    stage_w<1>(W1, B1, wlds, tid);
    stage_w<2>(W2, B2, wlds, tid);
    stage_w<3>(W3, B3, wlds, tid);
    stage_w<4>(W4, B4, wlds, tid);
    stage_w<5>(W5, B5, wlds, tid);
    stage_w<6>(W6, B6, wlds, tid);
    stage_w<7>(W7, B7, wlds, tid);
    stage_w<8>(W8, B8, wlds, tid);
    stage_w<9>(W9, B9, wlds, tid);
    stage_w<10>(W10, B10, wlds, tid);
    __syncthreads();

    const int wave = tid >> 6;
    const int lane = tid & 63;
    const int col  = lane & 15;
    const int quad = lane >> 4;
    const int pair = wave >> 1;
    const int sub  = wave & 1;
    short* buf = act + pair * ARENA;
    const int fo = quad * 128 + col * 8;

    // One-time arena zero (own 16-row half): keeps don't-care B regions
    // finite (NaN * 0-weight = NaN in MFMA).
    {
        u16x8 z = {0, 0, 0, 0, 0, 0, 0, 0};
#pragma unroll
        for (int i = 0; i < 4; ++i)
            *(u16x8*)(buf + sub * 2048 + (lane + i * 64) * 8) = z;
    }

    // Tail-layer weight frags in VGPRs (full-N; each wave uses its row-half).
    const bf16x8 w7  = *(const bf16x8*)(wlds + WOFF_[7]  + fo);
    const bf16x8 w8  = *(const bf16x8*)(wlds + WOFF_[8]  + fo);
    const bf16x8 w9  = *(const bf16x8*)(wlds + WOFF_[9]  + fo);
    const bf16x8 w10 = *(const bf16x8*)(wlds + WOFF_[10] + fo);

    // L2: this wave's 6 half-frags (channels [sub*48,(sub+1)*48)) in regs.
    bf16x8 wf2[6];
#pragma unroll
    for (int m = 0; m < 3; ++m)
#pragma unroll
        for (int kt = 0; kt < 2; ++kt)
            wf2[m * 2 + kt] = *(const bf16x8*)(wlds + WOFF_[2] + ((sub * 3 + m) * 2 + kt) * 512 + fo);

    int chunk = blockIdx.x;
    float4 xa;
    if (chunk < nchunks)
        fetch_x(x, chunk * ROWS_PER_BLOCK + pair * ROWS_PER_PAIR + sub * 16, col, quad, xa);

    for (; chunk < nchunks; chunk += gridDim.x) {
        const int row0 = chunk * ROWS_PER_BLOCK + pair * ROWS_PER_PAIR + sub * 16;
        stage_x(buf, xa, col, quad, sub);

        // Prefetch next chunk's x while the layer stack runs.
        const int nxt = chunk + gridDim.x;
        if (nxt < nchunks)
            fetch_x(x, nxt * ROWS_PER_BLOCK + pair * ROWS_PER_PAIR + sub * 16, col, quad, xa);

        __syncthreads();   // both halves staged before L0 reads them

        layer_pair<0>(wlds + WOFF_[0], buf, col, quad, sub);
        layer_pair<1>(wlds + WOFF_[1], buf, col, quad, sub);
        layer2_pair(wf2, buf, col, quad, sub);
        layer_pair<3>(wlds + WOFF_[3], buf, col, quad, sub);
        layer_pair<4>(wlds + WOFF_[4], buf, col, quad, sub);
        layer_pair<5>(wlds + WOFF_[5], buf, col, quad, sub);
        layer_pair<6>(wlds + WOFF_[6], buf, col, quad, sub);
        // Tails are row-split (own half only): no barriers needed.
        layer_one_half(w7, buf, col, quad, sub);
        layer_one_half(w8, buf, col, quad, sub);
        layer_one_half(w9, buf, col, quad, sub);

        // Final layer (5 -> 1, bias via pads) + sigmoid on own half.
        {
            bf16x8 b0 = *(const bf16x8*)(buf + sub * 512 + fo);
            f32x4 a0 = f32x4{0.f, 0.f, 0.f, 0.f};
            a0 = __builtin_amdgcn_mfma_f32_16x16x32_bf16(w10, b0, a0, 0, 0, 0);
            if (quad == 0)
                out[row0 + col] = 1.f / (1.f + __expf(-a0[0]));
        }
    }
}

extern "C" void kernel_launch(void* const* d_in, const int* in_sizes, int n_in,
                              void* d_out, int out_size, void* d_ws, size_t ws_size,
                              hipStream_t stream) {
    (void)n_in; (void)d_ws; (void)ws_size; (void)out_size;
    const float* x = (const float*)d_in[0];
    const float* W[11];
    const float* B[11];
    for (int i = 0; i < 11; ++i) {
        W[i] = (const float*)d_in[1 + 2 * i];
        B[i] = (const float*)d_in[2 + 2 * i];
    }
    const int nrows   = in_sizes[0] / 15;
    const int nchunks = nrows / ROWS_PER_BLOCK;   // 524288/256 = 2048

    hipFuncSetAttribute((const void*)mlp_fused,
                        hipFuncAttributeMaxDynamicSharedMemorySize, LDS_BYTES);

    mlp_fused<<<dim3(256), dim3(THREADS), LDS_BYTES, stream>>>(
        x,
        W[0], B[0], W[1], B[1], W[2], B[2], W[3], B[3], W[4], B[4],
        W[5], B[5], W[6], B[6], W[7], B[7], W[8], B[8], W[9], B[9],
        W[10], B[10],
        (float*)d_out, nchunks);
}